// Round 9
// baseline (155.241 us; speedup 1.0000x reference)
//
#include <hip/hip_runtime.h>
#include <cmath>

// ProtICU on MI355X — round 9: barrier-free conv pipeline.
// All convs read their B-operand directly from global (guard-padded bf16
// tensors in ws) in MFMA fragment layout — zero LDS staging, zero
// __syncthreads in the conv kernels -> waves fully independent, K-loop
// pipelines freely (no vmcnt(0)+barrier drains, the R4-R8 ceiling).
//  convert_x: x f32 (32,2048,76) -> xb bf16 (32, 2052, 96)  [2 guard rows each end]
//  conv1: xb -> h1 (32, 1028, 128);  conv2: h1 -> h2 (32, 516, 128)
//  conv3+head: h2 -> f (LDS) -> 1x1 GEMMs -> prototype distances -> atomicMin
//  finalize: min -> out. All GEMMs v_mfma_f32_16x16x32_bf16, fp32 acc.

typedef __attribute__((ext_vector_type(8))) short short8;
typedef __attribute__((ext_vector_type(4))) float f32x4;

__device__ __forceinline__ unsigned short f2bf(float v) {
    union { float f; unsigned u; } x; x.f = v;
    unsigned r = x.u + 0x7fffu + ((x.u >> 16) & 1u);   // RNE
    return (unsigned short)(r >> 16);
}
__device__ __forceinline__ float bf2f(unsigned short b) {
    union { unsigned u; float f; } x; x.u = ((unsigned)b) << 16;
    return x.f;
}

// ---------------------------------------------------------------------------
// convert_x: row p of batch b -> xb row p+2 (rows 0,1,2050,2051 are guards).
// ---------------------------------------------------------------------------
__global__ __launch_bounds__(256)
void convert_x_kernel(const float* __restrict__ x, unsigned short* __restrict__ xb)
{
    int t = blockIdx.x * 256 + threadIdx.x;      // 32*2048*12 threads
    int row = t / 12, c0 = (t % 12) * 8;
    int b = row >> 11, p = row & 2047;
    unsigned short v[8];
#pragma unroll
    for (int j = 0; j < 8; ++j) {
        int c = c0 + j;
        v[j] = (c < 76) ? f2bf(x[((size_t)b * 2048 + p) * 76 + c]) : (unsigned short)0;
    }
    *(uint4*)&xb[((size_t)b * 2052 + p + 2) * 96 + c0] = *(uint4*)v;
}

// ---------------------------------------------------------------------------
// Weight packing into MFMA A-fragment order (16x16x32):
// lane holds A[m = mf*16 + (lane&15)][k = cc*32 + (lane>>4)*8 + j]
// ---------------------------------------------------------------------------
__device__ void pack_conv_w(int t, int total, const float* __restrict__ W, int C,
                            unsigned short* __restrict__ dst)
{
    if (t >= total) return;
    int lane = t & 63, rest = t >> 6;
    int mf = rest & 7; rest >>= 3;
    int kk = rest % 5, cc = rest / 5;
    int m = mf * 16 + (lane & 15);
    int cb = cc * 32 + (lane >> 4) * 8;
    unsigned short v[8];
#pragma unroll
    for (int j = 0; j < 8; ++j) {
        int c = cb + j;
        v[j] = (c < C) ? f2bf(W[((size_t)m * C + c) * 5 + kk]) : (unsigned short)0;
    }
    *(uint4*)&dst[(size_t)t * 8] = *(uint4*)v;
}

__device__ void pack_mat(int t, const float* __restrict__ M, unsigned short* __restrict__ dst)
{
    if (t >= 2048) return;
    int lane = t & 63, mf = (t >> 6) & 7, cc = t >> 9;
    int m = mf * 16 + (lane & 15);
    int c0 = cc * 32 + (lane >> 4) * 8;
    unsigned short v[8];
#pragma unroll
    for (int j = 0; j < 8; ++j) v[j] = f2bf(M[(size_t)m * 128 + c0 + j]);
    *(uint4*)&dst[(size_t)t * 8] = *(uint4*)v;
}

__global__ __launch_bounds__(256)
void prep_weights_kernel(const float* __restrict__ W1, const float* __restrict__ W2,
                         const float* __restrict__ W3, const float* __restrict__ Wo1,
                         const float* __restrict__ Wo2, const float* __restrict__ protos,
                         unsigned short* A1, unsigned short* A2, unsigned short* A3,
                         unsigned short* AW1, unsigned short* AW2, unsigned short* AP,
                         float* pn, unsigned* pm_bits,
                         unsigned* xb_u, unsigned* h1_u, unsigned* h2_u)  // guard zeroing
{
    int t = blockIdx.x * 256 + threadIdx.x;      // 40*256 = 10240 per case
    switch (blockIdx.y) {
    case 0: pack_conv_w(t, 7680,  W1, 76,  A1); break;
    case 1: pack_conv_w(t, 10240, W2, 128, A2); break;
    case 2: pack_conv_w(t, 10240, W3, 128, A3); break;
    case 3: pack_mat(t, Wo1, AW1); break;
    case 4: pack_mat(t, Wo2, AW2); break;
    case 5: pack_mat(t, protos, AP); break;
    case 6:
        if (t < 128) {
            float s = 0.f;
            for (int d = 0; d < 128; ++d) {
                float v = bf2f(f2bf(protos[(size_t)t * 128 + d]));
                s = fmaf(v, v, s);
            }
            pn[t] = s;
        }
        break;
    case 7:
        if (t < 4096) pm_bits[t] = 0x7F800000u;   // +inf init for atomicMin
        break;
    case 8: {
        // zero guard rows (ws is re-poisoned 0xAA before every call)
        // xb: rows {0,1,2050,2051} x 96 ch -> 48 uints/row
        for (int i = t; i < 32 * 4 * 48; i += 10240) {
            int b = i / 192, rem = i % 192, rr = rem / 48, c2 = rem % 48;
            int r = (rr < 2) ? rr : 2048 + rr;
            xb_u[((size_t)b * 2052 + r) * 48 + c2] = 0u;
        }
        // h1: rows {0,1,1026,1027} x 128 ch -> 64 uints/row
        for (int i = t; i < 32 * 4 * 64; i += 10240) {
            int b = i / 256, rem = i % 256, rr = rem / 64, c2 = rem % 64;
            int r = (rr < 2) ? rr : 1024 + rr;
            h1_u[((size_t)b * 1028 + r) * 64 + c2] = 0u;
        }
        // h2: rows {0,1,514,515} x 128 ch
        for (int i = t; i < 32 * 4 * 64; i += 10240) {
            int b = i / 256, rem = i % 256, rr = rem / 64, c2 = rem % 64;
            int r = (rr < 2) ? rr : 512 + rr;
            h2_u[((size_t)b * 516 + r) * 64 + c2] = 0u;
        }
        break;
    }
    }
}

// ---------------------------------------------------------------------------
// Conv K-loop, B from GLOBAL. Bbase = in + (rowbase + lc)*RSTRIDE + lk.
// B(j, kk, cc) = Bbase[(j*16 + kk)*RSTRIDE + cc*32]. Fully unrolled, no syncs.
// ---------------------------------------------------------------------------
template <int NM, int NJ, int NCC, int RSTRIDE>
__device__ __forceinline__ void conv_g(const unsigned short* __restrict__ Af,
                                       const unsigned short* __restrict__ Bbase,
                                       int mf0, int lane, f32x4 (&acc)[NM][NJ])
{
#pragma unroll
    for (int i = 0; i < NM; ++i)
#pragma unroll
        for (int j = 0; j < NJ; ++j) acc[i][j] = (f32x4){0.f, 0.f, 0.f, 0.f};

#pragma unroll
    for (int cc = 0; cc < NCC; ++cc) {
#pragma unroll
        for (int kk = 0; kk < 5; ++kk) {
            const int step = cc * 5 + kk;
            short8 a[NM];
#pragma unroll
            for (int i = 0; i < NM; ++i)
                a[i] = *(const short8*)&Af[(((size_t)step * 8 + mf0 + i) * 64 + lane) * 8];
            short8 bb[NJ];
#pragma unroll
            for (int j = 0; j < NJ; ++j)
                bb[j] = *(const short8*)&Bbase[(size_t)(j * 16 + kk) * RSTRIDE + cc * 32];
#pragma unroll
            for (int j = 0; j < NJ; ++j)
#pragma unroll
                for (int i = 0; i < NM; ++i)
                    acc[i][j] = __builtin_amdgcn_mfma_f32_16x16x32_bf16(a[i], bb[j], acc[i][j], 0, 0, 0);
        }
    }
}

// conv epilogue: bias+relu+pool2, bf16 store to guard-padded (b, RO, 128) at row (p>>1)+2.
template <int NM, int NJ>
__device__ __forceinline__ void conv_epilogue(f32x4 (&acc)[NM][NJ],
                                              const float* __restrict__ bias,
                                              unsigned short* __restrict__ out,
                                              size_t outbase,   // (b*RO + 2) * 128
                                              int p0, int mf0, int lane)
{
    const int lc = lane & 15;
    const int lq = (lane >> 4) * 4;
#pragma unroll
    for (int i = 0; i < NM; ++i) {
        const int ch0 = (mf0 + i) * 16 + lq;
        const float4 bi = *(const float4*)&bias[ch0];
        const float bv[4] = {bi.x, bi.y, bi.z, bi.w};
#pragma unroll
        for (int j = 0; j < NJ; ++j) {
            const int p = p0 + j * 16 + lc;
            unsigned short pk[4];
#pragma unroll
            for (int r = 0; r < 4; ++r) {
                float v = fmaxf(acc[i][j][r] + bv[r], 0.f);
                float o = __shfl_xor(v, 1);
                pk[r] = f2bf(fmaxf(v, o));
            }
            if ((lc & 1) == 0)
                *(uint2*)&out[outbase + (size_t)(p >> 1) * 128 + ch0] = *(uint2*)pk;
        }
    }
}

// ---------------------------------------------------------------------------
// conv1: xb (32,2052,96) -> h1 (32,1028,128). Grid (16,32), 4 waves, no LDS.
// Wave (mg, ng): NM=4 m-frags (oc 64mg..+63) x NJ=4 (64 pre-pool rows).
// ---------------------------------------------------------------------------
__global__ __launch_bounds__(256, 2)
void conv1_kernel(const unsigned short* __restrict__ xb,
                  const unsigned short* __restrict__ A1,
                  const float* __restrict__ b1, unsigned short* __restrict__ h1)
{
    const int tid = threadIdx.x, lane = tid & 63, wid = tid >> 6;
    const int mg = wid & 1, ng = wid >> 1, mf0 = mg * 4;
    const int b = blockIdx.y;
    const int p0 = blockIdx.x * 128 + ng * 64;
    const int lc = lane & 15, lk = (lane >> 4) * 8;

    const unsigned short* Bbase = xb + ((size_t)b * 2052 + p0 + lc) * 96 + lk;
    f32x4 acc[4][4];
    conv_g<4, 4, 3, 96>(A1, Bbase, mf0, lane, acc);
    conv_epilogue<4, 4>(acc, b1, h1, ((size_t)b * 1028 + 2) * 128, p0, mf0, lane);
}

// ---------------------------------------------------------------------------
// conv2: h1 -> h2 (32,516,128). Grid (8,32), 4 waves, no LDS.
// ---------------------------------------------------------------------------
__global__ __launch_bounds__(256, 2)
void conv2_kernel(const unsigned short* __restrict__ h1,
                  const unsigned short* __restrict__ A2,
                  const float* __restrict__ b2, unsigned short* __restrict__ h2)
{
    const int tid = threadIdx.x, lane = tid & 63, wid = tid >> 6;
    const int mg = wid & 1, ng = wid >> 1, mf0 = mg * 4;
    const int b = blockIdx.y;
    const int p0 = blockIdx.x * 128 + ng * 64;
    const int lc = lane & 15, lk = (lane >> 4) * 8;

    const unsigned short* Bbase = h1 + ((size_t)b * 1028 + p0 + lc) * 128 + lk;
    f32x4 acc[4][4];
    conv_g<4, 4, 4, 128>(A2, Bbase, mf0, lane, acc);
    conv_epilogue<4, 4>(acc, b2, h2, ((size_t)b * 516 + 2) * 128, p0, mf0, lane);
}

// 1x1 GEMM over 32 head positions in s_f; wave owns 2 m-frags.
__device__ __forceinline__ void gemm_head(const unsigned short* __restrict__ Af,
                                          const unsigned short* __restrict__ s_f,
                                          int mf0h, int lane, f32x4 (&acc)[2][2])
{
    const int lc = lane & 15;
    const int lk = (lane >> 4) * 8;
#pragma unroll
    for (int i = 0; i < 2; ++i)
#pragma unroll
        for (int j = 0; j < 2; ++j) acc[i][j] = (f32x4){0.f, 0.f, 0.f, 0.f};
#pragma unroll
    for (int cc = 0; cc < 4; ++cc) {
        short8 a[2];
#pragma unroll
        for (int i = 0; i < 2; ++i)
            a[i] = *(const short8*)&Af[(((size_t)cc * 8 + mf0h + i) * 64 + lane) * 8];
        short8 bb[2];
#pragma unroll
        for (int j = 0; j < 2; ++j)
            bb[j] = *(const short8*)&s_f[(j * 16 + lc) * 136 + cc * 32 + lk];
#pragma unroll
        for (int i = 0; i < 2; ++i)
#pragma unroll
            for (int j = 0; j < 2; ++j)
                acc[i][j] = __builtin_amdgcn_mfma_f32_16x16x32_bf16(a[i], bb[j], acc[i][j], 0, 0, 0);
    }
}

// ---------------------------------------------------------------------------
// conv3 + head. Grid (8,32), 256 thr. conv3: 64 pre-pool rows -> 32 f rows in
// LDS (B from global h2, no staging). Head: 3 GEMMs + distances + atomicMin.
// ---------------------------------------------------------------------------
__global__ __launch_bounds__(256, 2)
void conv3_head_kernel(const unsigned short* __restrict__ h2,
                       const unsigned short* __restrict__ A3, const float* __restrict__ b3,
                       const unsigned short* __restrict__ AW1, const float* __restrict__ bo1,
                       const unsigned short* __restrict__ AW2, const float* __restrict__ bo2,
                       const unsigned short* __restrict__ AP,  const float* __restrict__ pn,
                       unsigned* __restrict__ pm_bits)
{
    __shared__ __align__(16) unsigned short s_f[32 * 136];
    __shared__ float s_part[4 * 32];
    __shared__ float s_fn[32];

    const int tid = threadIdx.x, lane = tid & 63, wid = tid >> 6;
    const int b = blockIdx.y;
    const int lc = lane & 15, lk = (lane >> 4) * 8;
    const int lq = (lane >> 4) * 4;

    // ---- conv3: wave (mg, ng): NM=4 x NJ=2 (32 rows) ----
    {
        const int mg = wid & 1, ng = wid >> 1, mf0 = mg * 4;
        const int p0 = blockIdx.x * 64 + ng * 32;
        const unsigned short* Bbase = h2 + ((size_t)b * 516 + p0 + lc) * 128 + lk;
        f32x4 acc[4][2];
        conv_g<4, 2, 4, 128>(A3, Bbase, mf0, lane, acc);

        // pool2 -> s_f local row (p>>1) - bx*32
#pragma unroll
        for (int i = 0; i < 4; ++i) {
            const int ch0 = (mf0 + i) * 16 + lq;
            const float4 bi = *(const float4*)&b3[ch0];
            const float bv[4] = {bi.x, bi.y, bi.z, bi.w};
#pragma unroll
            for (int j = 0; j < 2; ++j) {
                const int p = p0 + j * 16 + lc;
                unsigned short pk[4];
#pragma unroll
                for (int r = 0; r < 4; ++r) {
                    float v = fmaxf(acc[i][j][r] + bv[r], 0.f);
                    float o = __shfl_xor(v, 1);
                    pk[r] = f2bf(fmaxf(v, o));
                }
                if ((lc & 1) == 0)
                    *(uint2*)&s_f[(size_t)((p >> 1) - blockIdx.x * 32) * 136 + ch0] = *(uint2*)pk;
            }
        }
    }
    __syncthreads();   // f complete (32 positions x 128 ch)

    // ---- head: wave owns m-frags {2wid, 2wid+1} over all 32 positions ----
    const int mf0h = wid * 2;
    f32x4 hacc[2][2];

    gemm_head(AW1, s_f, mf0h, lane, hacc);     // t1 = relu(Wo1 f + bo1)
    __syncthreads();
#pragma unroll
    for (int i = 0; i < 2; ++i) {
        const int ch0 = (mf0h + i) * 16 + lq;
        const float4 bi = *(const float4*)&bo1[ch0];
        const float bv[4] = {bi.x, bi.y, bi.z, bi.w};
#pragma unroll
        for (int j = 0; j < 2; ++j) {
            unsigned short pk[4];
#pragma unroll
            for (int r = 0; r < 4; ++r)
                pk[r] = f2bf(fmaxf(hacc[i][j][r] + bv[r], 0.f));
            *(uint2*)&s_f[(j * 16 + lc) * 136 + ch0] = *(uint2*)pk;
        }
    }
    __syncthreads();

    gemm_head(AW2, s_f, mf0h, lane, hacc);     // t2 = relu(Wo2 t1 + bo2)
    __syncthreads();
#pragma unroll
    for (int i = 0; i < 2; ++i) {
        const int ch0 = (mf0h + i) * 16 + lq;
        const float4 bi = *(const float4*)&bo2[ch0];
        const float bv[4] = {bi.x, bi.y, bi.z, bi.w};
#pragma unroll
        for (int j = 0; j < 2; ++j) {
            unsigned short pk[4];
#pragma unroll
            for (int r = 0; r < 4; ++r)
                pk[r] = f2bf(fmaxf(hacc[i][j][r] + bv[r], 0.f));
            *(uint2*)&s_f[(j * 16 + lc) * 136 + ch0] = *(uint2*)pk;
        }
    }
    __syncthreads();

    // fn[n] = ||t2[n]||^2, n in [0,32)
    if (tid < 128) {
        int n = tid & 31, part = tid >> 5;
        float s = 0.f;
        for (int c = part * 32; c < part * 32 + 32; ++c) {
            float v = bf2f(s_f[n * 136 + c]);
            s = fmaf(v, v, s);
        }
        s_part[part * 32 + n] = s;
    }
    __syncthreads();
    if (tid < 32)
        s_fn[tid] = s_part[tid] + s_part[32 + tid] + s_part[64 + tid] + s_part[96 + tid];
    __syncthreads();

    gemm_head(AP, s_f, mf0h, lane, hacc);      // dot = P t2

#pragma unroll
    for (int i = 0; i < 2; ++i) {
#pragma unroll
        for (int r = 0; r < 4; ++r) {
            const int p = (mf0h + i) * 16 + lq + r;
            const float pnp = pn[p];
            float m = 3.0e38f;
#pragma unroll
            for (int j = 0; j < 2; ++j) {
                const int n = j * 16 + lc;
                float d2 = s_fn[n] + pnp - 2.f * hacc[i][j][r];
                m = fminf(m, sqrtf(fmaxf(d2, 1e-12f)));
            }
#pragma unroll
            for (int s = 1; s < 16; s <<= 1)
                m = fminf(m, __shfl_xor(m, s));
            if (lc == 0)
                atomicMin(&pm_bits[(size_t)b * 128 + p], __float_as_uint(m));
        }
    }
}

// ---------------------------------------------------------------------------
__global__ __launch_bounds__(128)
void finalize_kernel(const float* __restrict__ pm,       // (32,128) global min
                     const int* __restrict__ classes,
                     float* __restrict__ out)            // [64 sigmoid][4096 min_dis]
{
    __shared__ float r0[128], r1[128];
    const int b = blockIdx.x, p = threadIdx.x;
    float m = pm[(size_t)b * 128 + p];
    out[64 + b * 128 + p] = m;

    float sim = logf((m + 1.0f) / (m + 1e-4f));
    int cls = classes[p];
    r0[p] = (cls == 0) ? sim : -0.5f * sim;
    r1[p] = (cls == 1) ? sim : -0.5f * sim;
    __syncthreads();
    for (int s = 64; s > 0; s >>= 1) {
        if (p < s) { r0[p] += r0[p + s]; r1[p] += r1[p + s]; }
        __syncthreads();
    }
    if (p == 0) {
        out[b * 2 + 0] = 1.f / (1.f + expf(-r0[0]));
        out[b * 2 + 1] = 1.f / (1.f + expf(-r1[0]));
    }
}

// ---------------------------------------------------------------------------
extern "C" void kernel_launch(void* const* d_in, const int* in_sizes, int n_in,
                              void* d_out, int out_size, void* d_ws, size_t ws_size,
                              hipStream_t stream)
{
    (void)in_sizes; (void)n_in; (void)out_size; (void)ws_size;
    const float* x    = (const float*)d_in[0];
    const float* W1   = (const float*)d_in[1];
    const float* b1   = (const float*)d_in[2];
    const float* W2   = (const float*)d_in[3];
    const float* b2   = (const float*)d_in[4];
    const float* W3   = (const float*)d_in[5];
    const float* b3   = (const float*)d_in[6];
    const float* Wo1  = (const float*)d_in[7];
    const float* bo1  = (const float*)d_in[8];
    const float* Wo2  = (const float*)d_in[9];
    const float* bo2  = (const float*)d_in[10];
    const float* prot = (const float*)d_in[11];
    const int*   cls  = (const int*)d_in[12];
    float* out = (float*)d_out;

    // ws layout (bytes):
    //  xb @0: 32*2052*96*2   = 12,607,488
    //  h1 @12,607,488: 32*1028*128*2 = 8,421,376   -> ends 21,028,864
    //  h2 @21,028,864: 32*516*128*2  = 4,227,072   -> ends 25,255,936
    //  frags @25,296,896 (1 KB aligned)
    char* ws = (char*)d_ws;
    unsigned short* xb = (unsigned short*)(ws);
    unsigned short* h1 = (unsigned short*)(ws + 12607488);
    unsigned short* h2 = (unsigned short*)(ws + 21028864);
    const size_t FR = 25296896;
    unsigned short* A1  = (unsigned short*)(ws + FR);
    unsigned short* A2  = (unsigned short*)(ws + FR + 122880);
    unsigned short* A3  = (unsigned short*)(ws + FR + 286720);
    unsigned short* AW1 = (unsigned short*)(ws + FR + 450560);
    unsigned short* AW2 = (unsigned short*)(ws + FR + 483328);
    unsigned short* AP  = (unsigned short*)(ws + FR + 516096);
    float*          pn  = (float*)(ws + FR + 548864);
    unsigned*       pm  = (unsigned*)(ws + FR + 549376);

    convert_x_kernel<<<3072, 256, 0, stream>>>(x, xb);
    prep_weights_kernel<<<dim3(40, 9), 256, 0, stream>>>(W1, W2, W3, Wo1, Wo2, prot,
                                                         A1, A2, A3, AW1, AW2, AP, pn, pm,
                                                         (unsigned*)xb, (unsigned*)h1, (unsigned*)h2);
    conv1_kernel<<<dim3(16, 32), 256, 0, stream>>>(xb, A1, b1, h1);
    conv2_kernel<<<dim3(8, 32), 256, 0, stream>>>(h1, A2, b2, h2);
    conv3_head_kernel<<<dim3(8, 32), 256, 0, stream>>>(h2, A3, b3, AW1, bo1, AW2, bo2,
                                                       AP, pn, pm);
    finalize_kernel<<<32, 128, 0, stream>>>((const float*)pm, cls, out);
}